// Round 16
// baseline (719.169 us; speedup 1.0000x reference)
//
#include <hip/hip_runtime.h>
#include <stdint.h>

typedef __bf16 bf16x8 __attribute__((ext_vector_type(8)));
typedef float f32x4 __attribute__((ext_vector_type(4)));
typedef float f32x2 __attribute__((ext_vector_type(2)));

#define MFMA16(a, b, c) __builtin_amdgcn_mfma_f32_16x16x32_bf16((a), (b), (c), 0, 0, 0)

__device__ __forceinline__ float sigf(float x) { return 1.f / (1.f + __expf(-x)); }
__device__ __forceinline__ float tanhfast(float x) { return 1.f - 2.f / (__expf(2.f * x) + 1.f); }
__device__ __forceinline__ float bf2f(uint16_t u) {
  union { float f; uint32_t i; } v; v.i = ((uint32_t)u) << 16; return v.f;
}
__device__ __forceinline__ uint16_t f2bf(float f) {
  union { float f; uint32_t i; } v; v.f = f;
  return (uint16_t)((v.i + 0x7FFFu + ((v.i >> 16) & 1u)) >> 16);
}
// 8 consecutive f32 -> bf16x8 (RNE); p must be 16B-aligned
__device__ __forceinline__ bf16x8 cvt8(const float* __restrict__ p) {
  f32x4 a = *(const f32x4*)p;
  f32x4 b = *(const f32x4*)(p + 4);
  bf16x8 r;
  r[0] = (__bf16)a[0]; r[1] = (__bf16)a[1]; r[2] = (__bf16)a[2]; r[3] = (__bf16)a[3];
  r[4] = (__bf16)b[0]; r[5] = (__bf16)b[1]; r[6] = (__bf16)b[2]; r[7] = (__bf16)b[3];
  return r;
}

// ---------------------------------------------------------------------------
// K0: mf_W f32 [512][1000] -> bf16 padded [512][1024]
// ---------------------------------------------------------------------------
__global__ __launch_bounds__(256) void k_prep(
    const float* __restrict__ mf_W, uint16_t* __restrict__ mfWb) {
  const int idx = blockIdx.x * 256 + threadIdx.x;   // 524288 total
  const int h = idx >> 10, k = idx & 1023;
  const float v = (k < 1000) ? mf_W[(size_t)h * 1000 + k] : 0.f;
  mfWb[idx] = f2bf(v);
}

// ---------------------------------------------------------------------------
// K1: encWb[v][col] = bf16( sum_k enc_emb[v][k]*W_ih[col][k] + b_ih + b_hh )
// ---------------------------------------------------------------------------
__global__ __launch_bounds__(256) void k_encW(
    const float* __restrict__ enc_emb,   // [1002][512]
    const float* __restrict__ W_ih,      // [2048][512]
    const float* __restrict__ b_ih,
    const float* __restrict__ b_hh,
    uint16_t* __restrict__ encWb)        // [1002][2048] bf16
{
  const int w = threadIdx.x >> 6, l = threadIdx.x & 63;
  const int mblk = blockIdx.x & 15;
  const int nblk = blockIdx.x >> 4;
  const int kg = l >> 4;
  const int arow = mblk * 64 + w * 16 + (l & 15);
  const bool rowok = arow < 1002;

  f32x4 acc[4] = {};
  for (int kk = 0; kk < 16; ++kk) {
    const int kc = kk * 32 + kg * 8;
    bf16x8 a = {};
    if (rowok) a = cvt8(enc_emb + (size_t)arow * 512 + kc);
#pragma unroll
    for (int n = 0; n < 4; ++n) {
      const int wrow = nblk * 64 + n * 16 + (l & 15);
      bf16x8 b = cvt8(W_ih + (size_t)wrow * 512 + kc);
      acc[n] = MFMA16(a, b, acc[n]);
    }
  }
  const int orow = mblk * 64 + w * 16 + kg * 4;
#pragma unroll
  for (int n = 0; n < 4; ++n) {
    const int col = nblk * 64 + n * 16 + (l & 15);
    const float bias = b_ih[col] + b_hh[col];
#pragma unroll
    for (int j = 0; j < 4; ++j) {
      const int rrow = orow + j;
      if (rrow < 1002) encWb[(size_t)rrow * 2048 + col] = f2bf(acc[n][j] + bias);
    }
  }
}

// ---------------------------------------------------------------------------
// K2-FUSED (512-thread blocks): blocks 0..127 = scan (16 rowgroups x 8
//     h-slices of 64, 8 waves: wave=(gate,half)); blocks 128..927 = s-major
//     ext GEMM adapted to 512 threads (64 rows, 8 waves x 64 cols).
//     ROUND-15 CHANGE: fan-in 16 -> 8 producers (each wave polls exactly ONE
//     producer's tag-stripe); scan covers <=128 CUs so ext lands on scan-free
//     CUs (no issue-slot theft) and deadlock-freedom is unconditional
//     (>=128 CUs always available to ext regardless of dispatch order).
//     Tagged-data protocol byte-equivalent to round 13/14 (proof in r13).
// ---------------------------------------------------------------------------
__global__ __launch_bounds__(512, 2) void k_fused(
    const int* __restrict__ inp,        // [256][200]
    const float* __restrict__ W_hh,     // [2048][512] f32
    const uint16_t* __restrict__ encWb, // [1002][2048] bf16
    const int* __restrict__ uid, const int* __restrict__ sid,   // [51200]
    const float* __restrict__ user_emb,    // [50000][500]
    const float* __restrict__ skill_emb,   // [500][500]
    const uint16_t* __restrict__ mfWb,     // [512][1024] bf16
    const float* __restrict__ mf_b,        // [512]
    uint16_t* __restrict__ ext,         // [256*200][512] bf16
    uint16_t* __restrict__ hbuf,        // [2][256][512] bf16 tagged
    float* __restrict__ hfinal,         // [256][512] f32
    uint32_t* __restrict__ extCnt)      // [200] x 16-u32 stride (64B lines)
{
  __shared__ __align__(1024) char ldsbuf[65536];

  const int tid = threadIdx.x;          // 0..511
  const int w = tid >> 6, l = tid & 63, kg = l >> 4;

  if (blockIdx.x >= 128) {
    // ============ EXT role (s-major, 64 rows, 8 waves x 64 cols) ============
    char* As = ldsbuf;   // [64 rows][1024B], XOR-swizzled
    const int bx = blockIdx.x - 128;
    const int s  = bx >> 2;      // timestep 0..199 (early s dispatch first)
    const int bq = bx & 3;       // batch quarter

    const int srow = tid >> 3;   // 0..63 (row)
    const int q = tid & 7;       // 8 k-chunks of 64
    const int m = (bq * 64 + srow) * 200 + s;
    const float* up = user_emb + (size_t)uid[m] * 500;
    const float* sp = skill_emb + (size_t)sid[m] * 500;

    f32x4 acc[4][4] = {};

#pragma unroll
    for (int ks = 0; ks < 2; ++ks) {
      if (ks) __syncthreads();
#pragma unroll
      for (int j = 0; j < 8; ++j) {
        const int e0 = ks * 512 + q * 64 + j * 8;
        bf16x8 av = {};
        if (e0 + 8 <= 500) {
          av = cvt8(up + e0);
        } else if (e0 == 496) {
          f32x4 a4 = *(const f32x4*)(up + 496);
          f32x4 b4 = *(const f32x4*)sp;
          av[0] = (__bf16)a4[0]; av[1] = (__bf16)a4[1]; av[2] = (__bf16)a4[2]; av[3] = (__bf16)a4[3];
          av[4] = (__bf16)b4[0]; av[5] = (__bf16)b4[1]; av[6] = (__bf16)b4[2]; av[7] = (__bf16)b4[3];
        } else if (e0 + 8 <= 1000) {
          av = cvt8(sp + (e0 - 500));
        }
        const int kb = (q * 64 + j * 8) * 2;
        *(bf16x8*)(As + srow * 1024 + (kb ^ ((srow & 7) << 4))) = av;
      }
      __syncthreads();

      for (int kk = 0; kk < 16; ++kk) {
        bf16x8 a[4];
#pragma unroll
        for (int rf = 0; rf < 4; ++rf) {
          const int row = rf * 16 + (l & 15);
          a[rf] = *(const bf16x8*)(As + row * 1024 +
                                   ((kk * 64 + kg * 16) ^ ((row & 7) << 4)));
        }
#pragma unroll
        for (int n = 0; n < 4; ++n) {
          const int col = w * 64 + n * 16 + (l & 15);
          bf16x8 b = *(const bf16x8*)(mfWb + (size_t)col * 1024 + ks * 512 + kk * 32 + kg * 8);
#pragma unroll
          for (int rf = 0; rf < 4; ++rf)
            acc[rf][n] = MFMA16(a[rf], b, acc[rf][n]);
        }
      }
    }

#pragma unroll
    for (int rf = 0; rf < 4; ++rf)
#pragma unroll
      for (int n = 0; n < 4; ++n) {
        const int col = w * 64 + n * 16 + (l & 15);
        const float bias = mf_b[col];
#pragma unroll
        for (int j = 0; j < 4; ++j) {
          const int bl = rf * 16 + kg * 4 + j;
          const size_t grow = (size_t)(bq * 64 + bl) * 200 + s;
          ext[grow * 512 + col] = f2bf(acc[rf][n][j] + bias);
        }
      }
    asm volatile("s_waitcnt vmcnt(0)" ::: "memory");
    __syncthreads();
    if (tid == 0) {
      asm volatile("buffer_wbl2 sc1\n\ts_waitcnt vmcnt(0)" ::: "memory");
      __hip_atomic_fetch_add(extCnt + s * 16, 1u, __ATOMIC_RELAXED, __HIP_MEMORY_SCOPE_AGENT);
    }
    return;
  }

  // ============ SCAN role: 16 rowgroups x 8 h-slices(64), 8 waves ============
  uint16_t* htgS        = (uint16_t*)ldsbuf;                   // 16,384 B swizzled
  float (*gbuf)[16][66] = (float(*)[16][66])(ldsbuf + 16384);  // 16,896 B (pad 66)
  float (*ctS)[64]      = (float(*)[64])(ldsbuf + 33280);      //  4,096 B
  int (*inpS)[200]      = (int(*)[200])(ldsbuf + 37376);       // 12,800 B

  const int r  = blockIdx.x >> 3;         // rowgroup (16 batch rows)
  const int cs = blockIdx.x & 7;          // 64-h slice
  const int row0 = r * 16;
  const int g  = w >> 1;                  // gate (i,f,g,o)
  const int hf = w & 1;                   // 32-col half of the slice

  // W_hh fragments: gate g, cols cs*64 + hf*32 + n*16 (persistent, 128 VGPRs)
  bf16x8 wfrag[16][2];
#pragma unroll
  for (int kk = 0; kk < 16; ++kk) {
#pragma unroll
    for (int n = 0; n < 2; ++n) {
      const int wrow = g * 512 + cs * 64 + hf * 32 + n * 16 + (l & 15);
      wfrag[kk][n] = cvt8(W_hh + (size_t)wrow * 512 + kk * 32 + kg * 8);
    }
  }
  for (int e = tid; e < 1024; e += 512) ((float*)ctS)[e] = 0.f;
  for (int e = tid; e < 2048; e += 512) ((uint64_t*)htgS)[e] = 0ull;   // htg(0)=0
  for (int e = tid; e < 16 * 200; e += 512)
    inpS[e / 200][e % 200] = inp[(row0 + e / 200) * 200 + (e % 200)];

  const int grow_ = l >> 2;             // gather: row (16), 32B chunk gch (4)
  const int gch = l & 3;
  const int urr = tid >> 5;             // cell: row, 2 consecutive h of 64-slice
  const int uh2 = (tid & 31) << 1;
  const int ub = row0 + urr;

  __syncthreads();

  // ---- prologue: acc(t=0) from encWb; gated ep (ext[:,1]) via agent load
  f32x4 acc[2];
#pragma unroll
  for (int n = 0; n < 2; ++n)
#pragma unroll
    for (int j = 0; j < 4; ++j) {
      const int col = g * 512 + cs * 64 + hf * 32 + n * 16 + (l & 15);
      acc[n][j] = bf2f(encWb[(size_t)inpS[kg * 4 + j][0] * 2048 + col]);
    }
  while (__hip_atomic_load(extCnt + 16, __ATOMIC_RELAXED, __HIP_MEMORY_SCOPE_AGENT) < 4u)
    __builtin_amdgcn_s_sleep(1);
  uint32_t ep = __hip_atomic_load(
      (const uint32_t*)(ext + (size_t)ub * 200 * 512 + 512 + cs * 64 + uh2),
      __ATOMIC_RELAXED, __HIP_MEMORY_SCOPE_AGENT);

  for (int t = 0; t < 200; ++t) {
    // ---- gather h(t): wave w polls producer (r, w)'s stripe (ONE tag-set)
    if (t > 0) {
      const uint32_t tag = (uint32_t)((t >> 1) & 3);
      const uint64_t pat64 = ((uint64_t)((tag & 1u) | ((tag >> 1) << 16))) * 0x0000000100000001ull;
      const uint16_t* hb = hbuf + (size_t)(t & 1) * (256 * 512);
      // lane covers 32B: row grow_, cols w*64 + gch*16 .. +16
      const uint64_t* sp = (const uint64_t*)(hb + (size_t)(row0 + grow_) * 512 + w * 64 + gch * 16);
      uint64_t v[4];
#pragma unroll
      for (int q = 0; q < 4; ++q)
        v[q] = __hip_atomic_load(sp + q, __ATOMIC_RELAXED, __HIP_MEMORY_SCOPE_AGENT);
      while ((v[0] & 0x0001000100010001ull) != pat64 ||
             (v[1] & 0x0001000100010001ull) != pat64 ||
             (v[2] & 0x0001000100010001ull) != pat64 ||
             (v[3] & 0x0001000100010001ull) != pat64) {
        __builtin_amdgcn_s_sleep(1);
#pragma unroll
        for (int q = 0; q < 4; ++q)
          v[q] = __hip_atomic_load(sp + q, __ATOMIC_RELAXED, __HIP_MEMORY_SCOPE_AGENT);
      }
      // swizzled LDS writes (2-way max bank aliasing = free)
#pragma unroll
      for (int q = 0; q < 4; ++q) {
        const int o = w * 128 + gch * 32 + q * 8;    // byte offset within row
        *(uint64_t*)((char*)htgS + grow_ * 1024 + (o ^ ((grow_ & 7) << 4))) = v[q];
      }
    }
    __syncthreads();

    // ---- gates = acc(prefetched encW) + htg @ W_hh_slice^T
    const int ar = l & 15;
#pragma unroll
    for (int kk = 0; kk < 16; ++kk) {
      bf16x8 a = *(const bf16x8*)((char*)htgS + ar * 1024 +
                                  ((kk * 64 + kg * 16) ^ ((ar & 7) << 4)));
      acc[0] = MFMA16(a, wfrag[kk][0], acc[0]);
      acc[1] = MFMA16(a, wfrag[kk][1], acc[1]);
    }
#pragma unroll
    for (int n = 0; n < 2; ++n)
#pragma unroll
      for (int j = 0; j < 4; ++j)
        gbuf[g][kg * 4 + j][hf * 32 + n * 16 + (l & 15)] = acc[n][j];
    __syncthreads();

    // ---- cell update: thread -> (row urr, 2 consecutive h); TAGGED store
    {
      f32x2 sg[4];
#pragma unroll
      for (int gg_ = 0; gg_ < 4; ++gg_)
        sg[gg_] = *(const f32x2*)&gbuf[gg_][urr][uh2];

      float hv[2];
#pragma unroll
      for (int p = 0; p < 2; ++p) {
        const int h = uh2 + p;
        const float ig = sigf(sg[0][p]);
        const float fg = sigf(sg[1][p]);
        const float gg = tanhfast(sg[2][p]);
        const float og = sigf(sg[3][p]);
        const float cv = fg * ctS[urr][h] + ig * gg;
        ctS[urr][h] = cv;
        hv[p] = og * tanhfast(cv);
      }
      if (t < 199) {
        // pre-gate for step t+1: htg = ht * sigmoid(ext[:, t+1, :]);
        // embed gen tag ((t+1)>>1)&3 in the two bf16 LSBs (<=1 ulp each)
        const float g0 = sigf(bf2f((uint16_t)(ep & 0xFFFFu)));
        const float g1 = sigf(bf2f((uint16_t)(ep >> 16)));
        const uint32_t tagn = (uint32_t)(((t + 1) >> 1) & 3);
        const uint32_t tpat = (tagn & 1u) | ((tagn >> 1) << 16);
        uint32_t pk = (uint32_t)f2bf(hv[0] * g0) | ((uint32_t)f2bf(hv[1] * g1) << 16);
        pk = (pk & ~0x00010001u) | tpat;
        uint32_t* hw = (uint32_t*)(hbuf + (size_t)((t + 1) & 1) * (256 * 512) +
                                   (size_t)ub * 512 + cs * 64 + uh2);
        __hip_atomic_store(hw, pk, __ATOMIC_RELAXED, __HIP_MEMORY_SCOPE_AGENT);
      } else {
        hfinal[(size_t)ub * 512 + cs * 64 + uh2]     = hv[0];
        hfinal[(size_t)ub * 512 + cs * 64 + uh2 + 1] = hv[1];
      }
    }
    // NO drain, NO barrier, NO flag — tags carry the ordering.

    // ---- prefetch for step t+1 (hides under next step's tag-poll)
    if (t < 199) {
      const int tn = t + 1;
#pragma unroll
      for (int n = 0; n < 2; ++n)
#pragma unroll
        for (int j = 0; j < 4; ++j) {
          const int col = g * 512 + cs * 64 + hf * 32 + n * 16 + (l & 15);
          acc[n][j] = bf2f(encWb[(size_t)inpS[kg * 4 + j][tn] * 2048 + col]);
        }
      const int te = (t + 2 < 200) ? t + 2 : 199;
      while (__hip_atomic_load(extCnt + te * 16, __ATOMIC_RELAXED, __HIP_MEMORY_SCOPE_AGENT) < 4u)
        __builtin_amdgcn_s_sleep(1);
      ep = __hip_atomic_load(
          (const uint32_t*)(ext + (size_t)ub * 200 * 512 + (size_t)te * 512 + cs * 64 + uh2),
          __ATOMIC_RELAXED, __HIP_MEMORY_SCOPE_AGENT);
    }
  }
}

// ---------------------------------------------------------------------------
// K4: out[b] = sigmoid( dot(hfinal[b], dec_W[tgt[b]]) + dec_b[tgt[b]] )
// ---------------------------------------------------------------------------
__global__ __launch_bounds__(256) void k_dec(
    const float* __restrict__ hfinal,   // [256][512]
    const float* __restrict__ dec_W,    // [500][512]
    const float* __restrict__ dec_b,    // [500]
    const int* __restrict__ tgt,        // [256]
    float* __restrict__ out)            // [256]
{
  const int w = threadIdx.x >> 6, l = threadIdx.x & 63;
  const int b = blockIdx.x * 4 + w;
  const int t = tgt[b];
  float s = 0.f;
#pragma unroll
  for (int i = 0; i < 8; ++i) {
    const int k = l + i * 64;
    s += hfinal[(size_t)b * 512 + k] * dec_W[(size_t)t * 512 + k];
  }
#pragma unroll
  for (int m = 32; m; m >>= 1) s += __shfl_xor(s, m, 64);
  if (l == 0) out[b] = sigf(s + dec_b[t]);
}

// ---------------------------------------------------------------------------
extern "C" void kernel_launch(void* const* d_in, const int* in_sizes, int n_in,
                              void* d_out, int out_size, void* d_ws, size_t ws_size,
                              hipStream_t stream) {
  (void)in_sizes; (void)n_in; (void)out_size; (void)ws_size;
  const int*   inp       = (const int*)d_in[0];
  const int*   target_id = (const int*)d_in[1];
  const int*   uid       = (const int*)d_in[2];
  const int*   sid       = (const int*)d_in[3];
  // d_in[4] attempt_sequence: unused by reference
  const float* enc_emb   = (const float*)d_in[5];
  const float* user_emb  = (const float*)d_in[6];
  const float* skill_emb = (const float*)d_in[7];
  const float* mf_W      = (const float*)d_in[8];
  const float* mf_b      = (const float*)d_in[9];
  const float* W_ih      = (const float*)d_in[10];
  const float* W_hh      = (const float*)d_in[11];
  const float* b_ih      = (const float*)d_in[12];
  const float* b_hh      = (const float*)d_in[13];
  const float* dec_W     = (const float*)d_in[14];
  const float* dec_b     = (const float*)d_in[15];

  char* ws = (char*)d_ws;
  uint32_t* extCnt = (uint32_t*)(ws);                  //    12,800 B (padded s-counters)
  uint16_t* hbuf   = (uint16_t*)(ws + 16384);          //   524,288 B (bf16 tagged x2 buf)
  float*    hfinal = (float*)   (ws + 540672);         //   524,288 B
  uint16_t* encWb  = (uint16_t*)(ws + 1064960);        // 4,104,192 B (bf16)
  uint16_t* mfWb   = (uint16_t*)(ws + 5169152);        // 1,048,576 B
  uint16_t* ext    = (uint16_t*)(ws + 6217728);        // 52,428,800 B (total ~58.6 MB)

  // every call (in-graph => every replay): extCnt := 0; hbuf := 0xFF (tag=3,
  // never matches the first wanted tag 0 -> poison/replay-safe).
  hipMemsetAsync(extCnt, 0, 12800, stream);
  hipMemsetAsync(hbuf, 0xFF, 524288, stream);

  k_prep<<<2048, 256, 0, stream>>>(mf_W, mfWb);
  k_encW<<<512,  256, 0, stream>>>(enc_emb, W_ih, b_ih, b_hh, encWb);
  k_fused<<<928, 512, 0, stream>>>(inp, W_hh, encWb, uid, sid, user_emb, skill_emb,
                                   mfWb, mf_b, ext, hbuf, hfinal, extCnt);
  k_dec<<<64, 256, 0, stream>>>(hfinal, dec_W, dec_b, target_id, (float*)d_out);
}

// Round 17
// 684.633 us; speedup vs baseline: 1.0504x; 1.0504x over previous
//
#include <hip/hip_runtime.h>
#include <stdint.h>

typedef __bf16 bf16x8 __attribute__((ext_vector_type(8)));
typedef float f32x4 __attribute__((ext_vector_type(4)));

#define MFMA16(a, b, c) __builtin_amdgcn_mfma_f32_16x16x32_bf16((a), (b), (c), 0, 0, 0)

__device__ __forceinline__ float sigf(float x) { return 1.f / (1.f + __expf(-x)); }
__device__ __forceinline__ float tanhfast(float x) { return 1.f - 2.f / (__expf(2.f * x) + 1.f); }
__device__ __forceinline__ float bf2f(uint16_t u) {
  union { float f; uint32_t i; } v; v.i = ((uint32_t)u) << 16; return v.f;
}
__device__ __forceinline__ uint16_t f2bf(float f) {
  union { float f; uint32_t i; } v; v.f = f;
  return (uint16_t)((v.i + 0x7FFFu + ((v.i >> 16) & 1u)) >> 16);
}
// 8 consecutive f32 -> bf16x8 (RNE); p must be 16B-aligned
__device__ __forceinline__ bf16x8 cvt8(const float* __restrict__ p) {
  f32x4 a = *(const f32x4*)p;
  f32x4 b = *(const f32x4*)(p + 4);
  bf16x8 r;
  r[0] = (__bf16)a[0]; r[1] = (__bf16)a[1]; r[2] = (__bf16)a[2]; r[3] = (__bf16)a[3];
  r[4] = (__bf16)b[0]; r[5] = (__bf16)b[1]; r[6] = (__bf16)b[2]; r[7] = (__bf16)b[3];
  return r;
}

// ---------------------------------------------------------------------------
// K0: mf_W f32 [512][1000] -> bf16 padded [512][1024]
// ---------------------------------------------------------------------------
__global__ __launch_bounds__(256) void k_prep(
    const float* __restrict__ mf_W, uint16_t* __restrict__ mfWb) {
  const int idx = blockIdx.x * 256 + threadIdx.x;   // 524288 total
  const int h = idx >> 10, k = idx & 1023;
  const float v = (k < 1000) ? mf_W[(size_t)h * 1000 + k] : 0.f;
  mfWb[idx] = f2bf(v);
}

// ---------------------------------------------------------------------------
// K1: encWb[v][col] = bf16( sum_k enc_emb[v][k]*W_ih[col][k] + b_ih + b_hh )
// ---------------------------------------------------------------------------
__global__ __launch_bounds__(256) void k_encW(
    const float* __restrict__ enc_emb,   // [1002][512]
    const float* __restrict__ W_ih,      // [2048][512]
    const float* __restrict__ b_ih,
    const float* __restrict__ b_hh,
    uint16_t* __restrict__ encWb)        // [1002][2048] bf16
{
  const int w = threadIdx.x >> 6, l = threadIdx.x & 63;
  const int mblk = blockIdx.x & 15;
  const int nblk = blockIdx.x >> 4;
  const int kg = l >> 4;
  const int arow = mblk * 64 + w * 16 + (l & 15);
  const bool rowok = arow < 1002;

  f32x4 acc[4] = {};
  for (int kk = 0; kk < 16; ++kk) {
    const int kc = kk * 32 + kg * 8;
    bf16x8 a = {};
    if (rowok) a = cvt8(enc_emb + (size_t)arow * 512 + kc);
#pragma unroll
    for (int n = 0; n < 4; ++n) {
      const int wrow = nblk * 64 + n * 16 + (l & 15);
      bf16x8 b = cvt8(W_ih + (size_t)wrow * 512 + kc);
      acc[n] = MFMA16(a, b, acc[n]);
    }
  }
  const int orow = mblk * 64 + w * 16 + kg * 4;
#pragma unroll
  for (int n = 0; n < 4; ++n) {
    const int col = nblk * 64 + n * 16 + (l & 15);
    const float bias = b_ih[col] + b_hh[col];
#pragma unroll
    for (int j = 0; j < 4; ++j) {
      const int rrow = orow + j;
      if (rrow < 1002) encWb[(size_t)rrow * 2048 + col] = f2bf(acc[n][j] + bias);
    }
  }
}

// ---------------------------------------------------------------------------
// K2-FUSED: blocks 0..255 = scan (tagged-data protocol, parallel polls);
//     blocks 256..1055 = s-major ext GEMM. BEST-MEASURED CONFIG (round 14:
//     685us total, k_fused 672us). Structural floor of this decomposition:
//     200 sequential steps x (LLC store-visibility + poll-detect + compute)
//     ~= 3.4us/step; latency-bound (HBM 8%, Mfma 10%, VALU 17%). Fan-in
//     halving (r16) and K-split first-flag-start (r12) both measured <= 0.
// ---------------------------------------------------------------------------
__global__ __launch_bounds__(256, 2) void k_fused(
    const int* __restrict__ inp,        // [256][200]
    const float* __restrict__ W_hh,     // [2048][512] f32
    const uint16_t* __restrict__ encWb, // [1002][2048] bf16
    const int* __restrict__ uid, const int* __restrict__ sid,   // [51200]
    const float* __restrict__ user_emb,    // [50000][500]
    const float* __restrict__ skill_emb,   // [500][500]
    const uint16_t* __restrict__ mfWb,     // [512][1024] bf16
    const float* __restrict__ mf_b,        // [512]
    uint16_t* __restrict__ ext,         // [256*200][512] bf16
    uint16_t* __restrict__ hbuf,        // [2][256][512] bf16 tagged
    float* __restrict__ hfinal,         // [256][512] f32
    uint32_t* __restrict__ extCnt)      // [200] x 16-u32 stride (64B lines)
{
  __shared__ __align__(1024) char ldsbuf[65536];

  const int tid = threadIdx.x;
  const int w = tid >> 6, l = tid & 63, kg = l >> 4;

  if (blockIdx.x >= 256) {
    // ================= EXT role (s-major) =================
    char* As = ldsbuf;   // [64 rows][1024B], XOR-swizzled
    const int bx = blockIdx.x - 256;
    const int s  = bx >> 2;      // timestep 0..199
    const int bq = bx & 3;       // batch quarter

    const int srow = tid >> 2;
    const int q = tid & 3;
    const int m = (bq * 64 + srow) * 200 + s;
    const float* up = user_emb + (size_t)uid[m] * 500;
    const float* sp = skill_emb + (size_t)sid[m] * 500;

    f32x4 acc[4][8] = {};

#pragma unroll
    for (int ks = 0; ks < 2; ++ks) {
      if (ks) __syncthreads();
#pragma unroll
      for (int j = 0; j < 16; ++j) {
        const int e0 = ks * 512 + q * 128 + j * 8;
        bf16x8 av = {};
        if (e0 + 8 <= 500) {
          av = cvt8(up + e0);
        } else if (e0 == 496) {
          f32x4 a4 = *(const f32x4*)(up + 496);
          f32x4 b4 = *(const f32x4*)sp;
          av[0] = (__bf16)a4[0]; av[1] = (__bf16)a4[1]; av[2] = (__bf16)a4[2]; av[3] = (__bf16)a4[3];
          av[4] = (__bf16)b4[0]; av[5] = (__bf16)b4[1]; av[6] = (__bf16)b4[2]; av[7] = (__bf16)b4[3];
        } else if (e0 + 8 <= 1000) {
          av = cvt8(sp + (e0 - 500));
        }
        const int kb = (q * 128 + j * 8) * 2;
        *(bf16x8*)(As + srow * 1024 + (kb ^ ((srow & 7) << 4))) = av;
      }
      __syncthreads();

      for (int kk = 0; kk < 16; ++kk) {
        bf16x8 a[4];
#pragma unroll
        for (int rf = 0; rf < 4; ++rf) {
          const int row = rf * 16 + (l & 15);
          a[rf] = *(const bf16x8*)(As + row * 1024 +
                                   ((kk * 64 + kg * 16) ^ ((row & 7) << 4)));
        }
#pragma unroll
        for (int n = 0; n < 8; ++n) {
          const int col = w * 128 + n * 16 + (l & 15);
          bf16x8 b = *(const bf16x8*)(mfWb + (size_t)col * 1024 + ks * 512 + kk * 32 + kg * 8);
#pragma unroll
          for (int rf = 0; rf < 4; ++rf)
            acc[rf][n] = MFMA16(a[rf], b, acc[rf][n]);
        }
      }
    }

#pragma unroll
    for (int rf = 0; rf < 4; ++rf)
#pragma unroll
      for (int n = 0; n < 8; ++n) {
        const int col = w * 128 + n * 16 + (l & 15);
        const float bias = mf_b[col];
#pragma unroll
        for (int j = 0; j < 4; ++j) {
          const int bl = rf * 16 + kg * 4 + j;
          const size_t grow = (size_t)(bq * 64 + bl) * 200 + s;
          ext[grow * 512 + col] = f2bf(acc[rf][n][j] + bias);
        }
      }
    asm volatile("s_waitcnt vmcnt(0)" ::: "memory");
    __syncthreads();
    if (tid == 0) {
      asm volatile("buffer_wbl2 sc1\n\ts_waitcnt vmcnt(0)" ::: "memory");
      __hip_atomic_fetch_add(extCnt + s * 16, 1u, __ATOMIC_RELAXED, __HIP_MEMORY_SCOPE_AGENT);
    }
    return;
  }

  // ================= SCAN role (tagged exchange, parallel polls) =============
  uint16_t* htgS        = (uint16_t*)ldsbuf;                   // 16,384 B swizzled
  float (*gbuf)[16][32] = (float(*)[16][32])(ldsbuf + 16384);  //  8,192 B
  float (*ctS)[32]      = (float(*)[32])(ldsbuf + 24576);      //  2,048 B
  int (*inpS)[200]      = (int(*)[200])(ldsbuf + 26624);       // 12,800 B

  const int c = blockIdx.x & 15;          // h-slice (32 h)
  const int r = blockIdx.x >> 4;          // rowgroup (16 batch rows)
  const int row0 = r * 16;

  // W_hh slice -> bf16 register fragments (persistent, 128 VGPRs)
  bf16x8 wfrag[16][2];
#pragma unroll
  for (int kk = 0; kk < 16; ++kk) {
#pragma unroll
    for (int n = 0; n < 2; ++n) {
      const int wrow = w * 512 + c * 32 + n * 16 + (l & 15);
      wfrag[kk][n] = cvt8(W_hh + (size_t)wrow * 512 + kk * 32 + kg * 8);
    }
  }
  for (int e = tid; e < 512; e += 256) ctS[e >> 5][e & 31] = 0.f;
  for (int e = tid; e < 2048; e += 256) ((uint64_t*)htgS)[e] = 0ull;   // htg(0)=0
  for (int e = tid; e < 16 * 200; e += 256)
    inpS[e / 200][e % 200] = inp[(row0 + e / 200) * 200 + (e % 200)];

  const int grow_ = l >> 2;             // gather: row, 16B chunk
  const int gch = l & 3;
  const int urr = tid >> 4;             // cell: row, 2 consecutive h
  const int uh2 = (tid & 15) << 1;
  const int ub = row0 + urr;

  __syncthreads();

  // ---- prologue: acc(t=0) from encWb; gated ep (ext[:,1]) via agent load
  f32x4 acc[2];
#pragma unroll
  for (int n = 0; n < 2; ++n)
#pragma unroll
    for (int j = 0; j < 4; ++j) {
      const int col = w * 512 + c * 32 + n * 16 + (l & 15);
      acc[n][j] = bf2f(encWb[(size_t)inpS[kg * 4 + j][0] * 2048 + col]);
    }
  while (__hip_atomic_load(extCnt + 16, __ATOMIC_RELAXED, __HIP_MEMORY_SCOPE_AGENT) < 4u)
    __builtin_amdgcn_s_sleep(1);
  uint32_t ep = __hip_atomic_load(
      (const uint32_t*)(ext + (size_t)ub * 200 * 512 + 512 + c * 32 + uh2),
      __ATOMIC_RELAXED, __HIP_MEMORY_SCOPE_AGENT);

  for (int t = 0; t < 200; ++t) {
    // ---- gather h(t): PARALLEL-ISSUE tag-polls (all 8 loads before checks)
    if (t > 0) {
      const uint32_t tag = (uint32_t)((t >> 1) & 3);
      const uint64_t pat64 = ((uint64_t)((tag & 1u) | ((tag >> 1) << 16))) * 0x0000000100000001ull;
      const uint16_t* hb = hbuf + (size_t)(t & 1) * (256 * 512);
      const uint64_t* sp[4];
      uint64_t v[4][2];
#pragma unroll
      for (int p = 0; p < 4; ++p) {
        sp[p] = (const uint64_t*)(hb + (size_t)(row0 + grow_) * 512 + (w * 4 + p) * 32 + gch * 8);
        v[p][0] = __hip_atomic_load(sp[p],     __ATOMIC_RELAXED, __HIP_MEMORY_SCOPE_AGENT);
        v[p][1] = __hip_atomic_load(sp[p] + 1, __ATOMIC_RELAXED, __HIP_MEMORY_SCOPE_AGENT);
      }
#pragma unroll
      for (int p = 0; p < 4; ++p) {
        while ((v[p][0] & 0x0001000100010001ull) != pat64 ||
               (v[p][1] & 0x0001000100010001ull) != pat64) {
          __builtin_amdgcn_s_sleep(1);
          v[p][0] = __hip_atomic_load(sp[p],     __ATOMIC_RELAXED, __HIP_MEMORY_SCOPE_AGENT);
          v[p][1] = __hip_atomic_load(sp[p] + 1, __ATOMIC_RELAXED, __HIP_MEMORY_SCOPE_AGENT);
        }
      }
      // swizzled LDS writes (bank pattern: 2-way max = free)
#pragma unroll
      for (int p = 0; p < 4; ++p) {
        const int prod = w * 4 + p;
        const int baddr = grow_ * 1024 + (((prod * 64) + gch * 16) ^ ((grow_ & 7) << 4));
        *(uint64_t*)((char*)htgS + baddr)     = v[p][0];
        *(uint64_t*)((char*)htgS + baddr + 8) = v[p][1];
      }
    }
    __syncthreads();

    // ---- gates = acc(prefetched encW) + htg @ W_hh_slice^T
    const int ar = l & 15;
#pragma unroll
    for (int kk = 0; kk < 16; ++kk) {
      bf16x8 a = *(const bf16x8*)((char*)htgS + ar * 1024 +
                                  ((kk * 64 + kg * 16) ^ ((ar & 7) << 4)));
      acc[0] = MFMA16(a, wfrag[kk][0], acc[0]);
      acc[1] = MFMA16(a, wfrag[kk][1], acc[1]);
    }
#pragma unroll
    for (int n = 0; n < 2; ++n)
#pragma unroll
      for (int j = 0; j < 4; ++j)
        gbuf[w][kg * 4 + j][n * 16 + (l & 15)] = acc[n][j];
    __syncthreads();

    // ---- cell update: thread -> (row urr, 2 consecutive h); TAGGED store
    {
      float hv[2];
#pragma unroll
      for (int p = 0; p < 2; ++p) {
        const int h = uh2 + p;
        const float ig = sigf(gbuf[0][urr][h]);
        const float fg = sigf(gbuf[1][urr][h]);
        const float gg = tanhfast(gbuf[2][urr][h]);
        const float og = sigf(gbuf[3][urr][h]);
        const float cv = fg * ctS[urr][h] + ig * gg;
        ctS[urr][h] = cv;
        hv[p] = og * tanhfast(cv);
      }
      if (t < 199) {
        // pre-gate for step t+1: htg = ht * sigmoid(ext[:, t+1, :]);
        // embed gen tag ((t+1)>>1)&3 in the two bf16 LSBs (<=1 ulp each)
        const float g0 = sigf(bf2f((uint16_t)(ep & 0xFFFFu)));
        const float g1 = sigf(bf2f((uint16_t)(ep >> 16)));
        const uint32_t tagn = (uint32_t)(((t + 1) >> 1) & 3);
        const uint32_t tpat = (tagn & 1u) | ((tagn >> 1) << 16);
        uint32_t pk = (uint32_t)f2bf(hv[0] * g0) | ((uint32_t)f2bf(hv[1] * g1) << 16);
        pk = (pk & ~0x00010001u) | tpat;
        uint32_t* hw = (uint32_t*)(hbuf + (size_t)((t + 1) & 1) * (256 * 512) +
                                   (size_t)ub * 512 + c * 32 + uh2);
        __hip_atomic_store(hw, pk, __ATOMIC_RELAXED, __HIP_MEMORY_SCOPE_AGENT);
      } else {
        hfinal[(size_t)ub * 512 + c * 32 + uh2]     = hv[0];
        hfinal[(size_t)ub * 512 + c * 32 + uh2 + 1] = hv[1];
      }
    }
    // NO drain, NO barrier, NO flag — tags carry the ordering.

    // ---- prefetch for step t+1 (hides under next step's tag-poll)
    if (t < 199) {
      const int tn = t + 1;
#pragma unroll
      for (int n = 0; n < 2; ++n)
#pragma unroll
        for (int j = 0; j < 4; ++j) {
          const int col = w * 512 + c * 32 + n * 16 + (l & 15);
          acc[n][j] = bf2f(encWb[(size_t)inpS[kg * 4 + j][tn] * 2048 + col]);
        }
      const int te = (t + 2 < 200) ? t + 2 : 199;
      while (__hip_atomic_load(extCnt + te * 16, __ATOMIC_RELAXED, __HIP_MEMORY_SCOPE_AGENT) < 4u)
        __builtin_amdgcn_s_sleep(1);
      ep = __hip_atomic_load(
          (const uint32_t*)(ext + (size_t)ub * 200 * 512 + (size_t)te * 512 + c * 32 + uh2),
          __ATOMIC_RELAXED, __HIP_MEMORY_SCOPE_AGENT);
    }
  }
}

// ---------------------------------------------------------------------------
// K4: out[b] = sigmoid( dot(hfinal[b], dec_W[tgt[b]]) + dec_b[tgt[b]] )
// ---------------------------------------------------------------------------
__global__ __launch_bounds__(256) void k_dec(
    const float* __restrict__ hfinal,   // [256][512]
    const float* __restrict__ dec_W,    // [500][512]
    const float* __restrict__ dec_b,    // [500]
    const int* __restrict__ tgt,        // [256]
    float* __restrict__ out)            // [256]
{
  const int w = threadIdx.x >> 6, l = threadIdx.x & 63;
  const int b = blockIdx.x * 4 + w;
  const int t = tgt[b];
  float s = 0.f;
#pragma unroll
  for (int i = 0; i < 8; ++i) {
    const int k = l + i * 64;
    s += hfinal[(size_t)b * 512 + k] * dec_W[(size_t)t * 512 + k];
  }
#pragma unroll
  for (int m = 32; m; m >>= 1) s += __shfl_xor(s, m, 64);
  if (l == 0) out[b] = sigf(s + dec_b[t]);
}

// ---------------------------------------------------------------------------
extern "C" void kernel_launch(void* const* d_in, const int* in_sizes, int n_in,
                              void* d_out, int out_size, void* d_ws, size_t ws_size,
                              hipStream_t stream) {
  (void)in_sizes; (void)n_in; (void)out_size; (void)ws_size;
  const int*   inp       = (const int*)d_in[0];
  const int*   target_id = (const int*)d_in[1];
  const int*   uid       = (const int*)d_in[2];
  const int*   sid       = (const int*)d_in[3];
  // d_in[4] attempt_sequence: unused by reference
  const float* enc_emb   = (const float*)d_in[5];
  const float* user_emb  = (const float*)d_in[6];
  const float* skill_emb = (const float*)d_in[7];
  const float* mf_W      = (const float*)d_in[8];
  const float* mf_b      = (const float*)d_in[9];
  const float* W_ih      = (const float*)d_in[10];
  const float* W_hh      = (const float*)d_in[11];
  const float* b_ih      = (const float*)d_in[12];
  const float* b_hh      = (const float*)d_in[13];
  const float* dec_W     = (const float*)d_in[14];
  const float* dec_b     = (const float*)d_in[15];

  char* ws = (char*)d_ws;
  uint32_t* extCnt = (uint32_t*)(ws);                  //    12,800 B (padded s-counters)
  uint16_t* hbuf   = (uint16_t*)(ws + 16384);          //   524,288 B (bf16 tagged x2 buf)
  float*    hfinal = (float*)   (ws + 540672);         //   524,288 B
  uint16_t* encWb  = (uint16_t*)(ws + 1064960);        // 4,104,192 B (bf16)
  uint16_t* mfWb   = (uint16_t*)(ws + 5169152);        // 1,048,576 B
  uint16_t* ext    = (uint16_t*)(ws + 6217728);        // 52,428,800 B (total ~58.6 MB)

  // every call (in-graph => every replay): extCnt := 0; hbuf := 0xFF (tag=3,
  // never matches the first wanted tag 0 -> poison/replay-safe).
  hipMemsetAsync(extCnt, 0, 12800, stream);
  hipMemsetAsync(hbuf, 0xFF, 524288, stream);

  k_prep<<<2048, 256, 0, stream>>>(mf_W, mfWb);
  k_encW<<<512,  256, 0, stream>>>(enc_emb, W_ih, b_ih, b_hh, encWb);
  k_fused<<<1056, 256, 0, stream>>>(inp, W_hh, encWb, uid, sid, user_emb, skill_emb,
                                    mfWb, mf_b, ext, hbuf, hfinal, extCnt);
  k_dec<<<64, 256, 0, stream>>>(hfinal, dec_W, dec_b, target_id, (float*)d_out);
}